// Round 1
// baseline (276.061 us; speedup 1.0000x reference)
//
#include <hip/hip_runtime.h>

#define C_DIM 256
#define N_DIM 16384
#define NBATCH 8

typedef __bf16 bf16x4 __attribute__((ext_vector_type(4)));
typedef __bf16 bf16x8 __attribute__((ext_vector_type(8)));
typedef float  f32x4  __attribute__((ext_vector_type(4)));

// ---- workspace layout (bytes) ----
#define OFF_G   0x000000u   // G:  8 x 256 x 256 f32 (2 MiB), atomically accumulated
#define OFF_S   0x200000u   // s:  8 x 256 f32 (row sums of X)
#define OFF_EK  0x202000u   // ek: 8 x 256 f32
#define OFF_EQ  0x204000u   // eq: 8 x 256 f32
#define OFF_D   0x206000u   // d:  8 x 256 f32
#define OFF_T1  0x210000u   // T1: 8 x 256 x 256 f32 (2 MiB)
#define OFF_E   0x410000u   // energy / attention in-place: 8 x 256 x 256 f32 (2 MiB)
#define OFF_P   0x610000u   // P' = gamma*AttT*Wv + I : 8 x 256 x 256 bf16 (1 MiB)

// XOR swizzle for [row][64 x bf16] LDS tiles (128 B rows).
// Makes both b64 staging writes and b128 fragment reads hit the bank floor.
__device__ __forceinline__ unsigned sw_off(int row, int kbyte) {
  return (unsigned)(row * 128 + (kbyte ^ ((((row >> 2) ^ row) & 7) << 4)));
}
__device__ __forceinline__ float f4g(const float4& v, int i) {
  return reinterpret_cast<const float*>(&v)[i];
}

// ============================================================================
// K1: G[b] += X_b X_b^T  (bf16 MFMA, split-K over N, 3 quadrants via symmetry)
//     also s[b][c] = sum_n X[b][c][n] (diagonal-quadrant blocks only)
// grid (16 splitk chunks, 3 quadrants, 8 batches), block 256 (4 waves, 2x2 of 64x64)
// ============================================================================
__global__ __launch_bounds__(256) void k1_gram(const float* __restrict__ x,
                                               float* __restrict__ G,
                                               float* __restrict__ srow) {
  __shared__ __align__(16) char lds[2 * 128 * 128];
  __shared__ float s_lds[128];
  const int qi = blockIdx.y;
  const int qa = (qi == 2) ? 1 : 0;        // quadrants: (0,0),(0,1),(1,1)
  const int qb = (qi == 0) ? 0 : 1;
  const bool diag = (qa == qb);
  const int b = blockIdx.z;
  const float* xb = x + (size_t)b * C_DIM * N_DIM;
  const int tid = threadIdx.x, lane = tid & 63, wave = tid >> 6;
  const int wm = wave >> 1, wn = wave & 1;
  char* Alds = lds;
  char* Blds = lds + 16384;
  const int k4 = tid & 15, rowt = tid >> 4;
  float spart[8];
#pragma unroll
  for (int p = 0; p < 8; ++p) spart[p] = 0.f;
  f32x4 acc[4][4] = {};
  const size_t nbase = (size_t)blockIdx.x * 1024;   // 16 chunks x 1024 = 16384

  for (int ks = 0; ks < 16; ++ks) {
    const size_t n0 = nbase + (size_t)ks * 64 + 4 * k4;
    float4 va[8], vb[8];
#pragma unroll
    for (int p = 0; p < 8; ++p) {
      const int row = rowt + p * 16;
      va[p] = *(const float4*)&xb[(size_t)(qa * 128 + row) * N_DIM + n0];
      if (!diag) vb[p] = *(const float4*)&xb[(size_t)(qb * 128 + row) * N_DIM + n0];
    }
    __syncthreads();
#pragma unroll
    for (int p = 0; p < 8; ++p) {
      const int row = rowt + p * 16;
      if (diag) spart[p] += va[p].x + va[p].y + va[p].z + va[p].w;
      bf16x4 ha = { (__bf16)va[p].x, (__bf16)va[p].y, (__bf16)va[p].z, (__bf16)va[p].w };
      *(bf16x4*)(Alds + sw_off(row, 8 * k4)) = ha;
      if (!diag) {
        bf16x4 hb = { (__bf16)vb[p].x, (__bf16)vb[p].y, (__bf16)vb[p].z, (__bf16)vb[p].w };
        *(bf16x4*)(Blds + sw_off(row, 8 * k4)) = hb;
      }
    }
    __syncthreads();
    const char* Bsrc = diag ? Alds : Blds;
#pragma unroll
    for (int kk = 0; kk < 2; ++kk) {
      bf16x8 af[4], bfr[4];
      const int kbyte = (kk * 32 + (lane >> 4) * 8) * 2;
#pragma unroll
      for (int mi = 0; mi < 4; ++mi)
        af[mi] = *(const bf16x8*)(Alds + sw_off(wm * 64 + mi * 16 + (lane & 15), kbyte));
#pragma unroll
      for (int ni = 0; ni < 4; ++ni)
        bfr[ni] = *(const bf16x8*)(Bsrc + sw_off(wn * 64 + ni * 16 + (lane & 15), kbyte));
#pragma unroll
      for (int mi = 0; mi < 4; ++mi)
#pragma unroll
        for (int ni = 0; ni < 4; ++ni)
          acc[mi][ni] = __builtin_amdgcn_mfma_f32_16x16x32_bf16(af[mi], bfr[ni], acc[mi][ni], 0, 0, 0);
    }
  }

  float* Gb = G + (size_t)b * 65536;
#pragma unroll
  for (int mi = 0; mi < 4; ++mi)
#pragma unroll
    for (int ni = 0; ni < 4; ++ni)
#pragma unroll
      for (int r = 0; r < 4; ++r) {
        const int gr = qa * 128 + wm * 64 + mi * 16 + (lane >> 4) * 4 + r;
        const int gc = qb * 128 + wn * 64 + ni * 16 + (lane & 15);
        atomicAdd(&Gb[gr * 256 + gc], acc[mi][ni][r]);
      }

  if (diag) {
    __syncthreads();
    if (tid < 128) s_lds[tid] = 0.f;
    __syncthreads();
#pragma unroll
    for (int p = 0; p < 8; ++p) atomicAdd(&s_lds[rowt + p * 16], spart[p]);
    __syncthreads();
    if (tid < 128) atomicAdd(&srow[b * 256 + qa * 128 + tid], s_lds[tid]);
  }
}

// Mirror lower-left quadrant of symmetric G
__global__ void k1_mirror(float* __restrict__ G) {
  const int b = blockIdx.y;
  const int idx = blockIdx.x * 256 + threadIdx.x;   // 0..16383
  const int a = idx >> 7, c = idx & 127;
  float* Gb = G + (size_t)b * 65536;
  Gb[(size_t)(128 + c) * 256 + a] = Gb[(size_t)a * 256 + 128 + c];
}

// ek = Wk*s, eq = Wq*s (bias rank-1 helpers)
__global__ void k2_vec(const float* __restrict__ Wq, const float* __restrict__ Wk,
                       const float* __restrict__ s, float* __restrict__ ek,
                       float* __restrict__ eq) {
  const int b = blockIdx.x, t = threadIdx.x;
  const float* sb = s + b * 256;
  if (t < 256) {
    float a = 0.f;
    for (int i = 0; i < 256; ++i) a += Wk[t * 256 + i] * sb[i];
    ek[b * 256 + t] = a;
  } else {
    const int j = t - 256;
    float a = 0.f;
    for (int i = 0; i < 256; ++i) a += Wq[j * 256 + i] * sb[i];
    eq[b * 256 + j] = a;
  }
}

// NT mini-GEMM: C[i][j] = sum_k A[i][k] * B[j][k]   (256x256x256, fp32)
// used for T1 = Wk*G (G symmetric -> read rows) and energy = T1*Wq^T (+ bias)
__global__ __launch_bounds__(256) void k2_nt(const float* __restrict__ Ag, int abatch,
                                             const float* __restrict__ Bg, int bbatch,
                                             float* __restrict__ Cg,
                                             const float* __restrict__ ek,
                                             const float* __restrict__ bq,
                                             const float* __restrict__ bk,
                                             const float* __restrict__ eq,
                                             float Nf, int bias) {
  const int b = blockIdx.z;
  const float* A = Ag + (abatch ? (size_t)b * 65536 : 0);
  const float* B = Bg + (bbatch ? (size_t)b * 65536 : 0);
  float* Cb = Cg + (size_t)b * 65536;
  const int i0 = blockIdx.y * 64 + 4 * (threadIdx.x >> 4);
  const int c0 = blockIdx.x * 64 + 4 * (threadIdx.x & 15);
  float acc[4][4] = {};
  for (int k = 0; k < 256; k += 4) {
    float4 av[4], bv4[4];
#pragma unroll
    for (int r = 0; r < 4; ++r) av[r] = *(const float4*)&A[(size_t)(i0 + r) * 256 + k];
#pragma unroll
    for (int s2 = 0; s2 < 4; ++s2) bv4[s2] = *(const float4*)&B[(size_t)(c0 + s2) * 256 + k];
#pragma unroll
    for (int r = 0; r < 4; ++r)
#pragma unroll
      for (int s2 = 0; s2 < 4; ++s2)
        acc[r][s2] += av[r].x * bv4[s2].x + av[r].y * bv4[s2].y +
                      av[r].z * bv4[s2].z + av[r].w * bv4[s2].w;
  }
#pragma unroll
  for (int r = 0; r < 4; ++r)
#pragma unroll
    for (int s2 = 0; s2 < 4; ++s2) {
      const int i = i0 + r, j = c0 + s2;
      float v = acc[r][s2];
      if (bias) v += ek[b * 256 + i] * bq[j] + bk[i] * (eq[b * 256 + j] + Nf * bq[j]);
      Cb[(size_t)i * 256 + j] = v;
    }
}

// row-softmax over last axis, in place. One wave per 256-float row.
__global__ __launch_bounds__(256) void k2_softmax(float* __restrict__ E) {
  const int gw = blockIdx.x * 4 + (threadIdx.x >> 6);   // 0..2047
  const int b = gw >> 8, i = gw & 255;
  const int lane = threadIdx.x & 63;
  float* row = E + (size_t)b * 65536 + (size_t)i * 256;
  float4 v = *(const float4*)&row[lane * 4];
  float m = fmaxf(fmaxf(v.x, v.y), fmaxf(v.z, v.w));
  for (int o = 32; o > 0; o >>= 1) m = fmaxf(m, __shfl_xor(m, o));
  v.x = __expf(v.x - m); v.y = __expf(v.y - m);
  v.z = __expf(v.z - m); v.w = __expf(v.w - m);
  float sum = v.x + v.y + v.z + v.w;
  for (int o = 32; o > 0; o >>= 1) sum += __shfl_xor(sum, o);
  const float inv = 1.0f / sum;
  v.x *= inv; v.y *= inv; v.z *= inv; v.w *= inv;
  *(float4*)&row[lane * 4] = v;
}

// P'[j][c] = gamma * sum_i Att[i][j] * Wv[i][c] + (j==c), stored bf16
__global__ __launch_bounds__(256) void k2_pprime(const float* __restrict__ Att,
                                                 const float* __restrict__ Wv,
                                                 const float* __restrict__ gm,
                                                 __bf16* __restrict__ P) {
  const int b = blockIdx.z;
  const float* Ab = Att + (size_t)b * 65536;
  const int j0 = blockIdx.y * 64 + 4 * (threadIdx.x >> 4);
  const int c0 = blockIdx.x * 64 + 4 * (threadIdx.x & 15);
  float acc[4][4] = {};
#pragma unroll 4
  for (int i = 0; i < 256; ++i) {
    float4 av = *(const float4*)&Ab[(size_t)i * 256 + j0];
    float4 wv = *(const float4*)&Wv[(size_t)i * 256 + c0];
#pragma unroll
    for (int r = 0; r < 4; ++r) {
      const float a = f4g(av, r);
#pragma unroll
      for (int s2 = 0; s2 < 4; ++s2) acc[r][s2] += a * f4g(wv, s2);
    }
  }
  const float g = gm[0];
  __bf16* Pb = P + (size_t)b * 65536;
#pragma unroll
  for (int r = 0; r < 4; ++r)
#pragma unroll
    for (int s2 = 0; s2 < 4; ++s2) {
      const float v = g * acc[r][s2] + ((j0 + r) == (c0 + s2) ? 1.f : 0.f);
      Pb[(size_t)(j0 + r) * 256 + c0 + s2] = (__bf16)v;
    }
}

// d[j] = gamma * sum_i Att[i][j] * bv[i]
__global__ void k2_dvec(const float* __restrict__ Att, const float* __restrict__ bv,
                        const float* __restrict__ gm, float* __restrict__ dv) {
  const int b = blockIdx.x, j = threadIdx.x;
  const float* Ab = Att + (size_t)b * 65536;
  float a = 0.f;
  for (int i = 0; i < 256; ++i) a += Ab[(size_t)i * 256 + j] * bv[i];
  dv[b * 256 + j] = gm[0] * a;
}

// ============================================================================
// K3: out[b] = P'_b * X_b + d 1^T  (bf16 MFMA; residual+gamma folded into P')
// grid (128 n-tiles, 2 j-tiles, 8 batches), block 256 (4 waves, 2x2 of 64x64)
// B-operand is x transposed+converted on the fly (4x4 register transpose).
// ============================================================================
__global__ __launch_bounds__(256) void k3_out(const float* __restrict__ x,
                                              const __bf16* __restrict__ P,
                                              const float* __restrict__ dvec,
                                              float* __restrict__ out) {
  __shared__ __align__(16) char lds[2 * 128 * 128];
  const int b = blockIdx.z, jt = blockIdx.y, nt = blockIdx.x;
  const float* xb = x + (size_t)b * C_DIM * N_DIM;
  const __bf16* Pb = P + (size_t)b * 65536;
  const int tid = threadIdx.x, lane = tid & 63, wave = tid >> 6;
  const int wm = wave >> 1, wn = wave & 1;
  char* Alds = lds;          // P' tile: [128 j][64 c]
  char* Blds = lds + 16384;  // Xt tile: [128 n][64 c]
  const int k4 = tid & 15, rowt = tid >> 4;
  const int nq = tid & 31, cq = tid >> 5;
  const int n0 = nt * 128;
  f32x4 acc[4][4] = {};

  for (int ks = 0; ks < 4; ++ks) {
    const int c0 = ks * 64;
    bf16x4 pa[8];
    float4 xv[2][4];
#pragma unroll
    for (int p = 0; p < 8; ++p)
      pa[p] = *(const bf16x4*)&Pb[(size_t)(jt * 128 + rowt + p * 16) * 256 + c0 + 4 * k4];
#pragma unroll
    for (int h = 0; h < 2; ++h) {
      const int cc = c0 + 4 * cq + 32 * h;
#pragma unroll
      for (int r = 0; r < 4; ++r)
        xv[h][r] = *(const float4*)&xb[(size_t)(cc + r) * N_DIM + n0 + 4 * nq];
    }
    __syncthreads();
#pragma unroll
    for (int p = 0; p < 8; ++p)
      *(bf16x4*)(Alds + sw_off(rowt + p * 16, 8 * k4)) = pa[p];
#pragma unroll
    for (int h = 0; h < 2; ++h) {
      const int cb = (4 * cq + 32 * h) * 2;   // byte offset of c within row
#pragma unroll
      for (int i = 0; i < 4; ++i) {           // 4x4 register transpose
        bf16x4 t = { (__bf16)f4g(xv[h][0], i), (__bf16)f4g(xv[h][1], i),
                     (__bf16)f4g(xv[h][2], i), (__bf16)f4g(xv[h][3], i) };
        *(bf16x4*)(Blds + sw_off(4 * nq + i, cb)) = t;
      }
    }
    __syncthreads();
#pragma unroll
    for (int kk = 0; kk < 2; ++kk) {
      bf16x8 af[4], bfr[4];
      const int kbyte = (kk * 32 + (lane >> 4) * 8) * 2;
#pragma unroll
      for (int mi = 0; mi < 4; ++mi)
        af[mi] = *(const bf16x8*)(Alds + sw_off(wm * 64 + mi * 16 + (lane & 15), kbyte));
#pragma unroll
      for (int ni = 0; ni < 4; ++ni)
        bfr[ni] = *(const bf16x8*)(Blds + sw_off(wn * 64 + ni * 16 + (lane & 15), kbyte));
#pragma unroll
      for (int mi = 0; mi < 4; ++mi)
#pragma unroll
        for (int ni = 0; ni < 4; ++ni)
          acc[mi][ni] = __builtin_amdgcn_mfma_f32_16x16x32_bf16(af[mi], bfr[ni], acc[mi][ni], 0, 0, 0);
    }
  }

  float* ob = out + (size_t)b * C_DIM * N_DIM;
#pragma unroll
  for (int mi = 0; mi < 4; ++mi)
#pragma unroll
    for (int ni = 0; ni < 4; ++ni)
#pragma unroll
      for (int r = 0; r < 4; ++r) {
        const int j = jt * 128 + wm * 64 + mi * 16 + (lane >> 4) * 4 + r;
        const int n = n0 + wn * 64 + ni * 16 + (lane & 15);
        ob[(size_t)j * N_DIM + n] = acc[mi][ni][r] + dvec[b * 256 + j];
      }
}

extern "C" void kernel_launch(void* const* d_in, const int* in_sizes, int n_in,
                              void* d_out, int out_size, void* d_ws, size_t ws_size,
                              hipStream_t stream) {
  const float* x  = (const float*)d_in[0];
  const float* Wq = (const float*)d_in[1];
  const float* bq = (const float*)d_in[2];
  const float* Wk = (const float*)d_in[3];
  const float* bk = (const float*)d_in[4];
  const float* Wv = (const float*)d_in[5];
  const float* bv = (const float*)d_in[6];
  const float* gm = (const float*)d_in[7];
  float* out = (float*)d_out;
  char* ws = (char*)d_ws;
  float* G  = (float*)(ws + OFF_G);
  float* s  = (float*)(ws + OFF_S);
  float* ek = (float*)(ws + OFF_EK);
  float* eq = (float*)(ws + OFF_EQ);
  float* dv = (float*)(ws + OFF_D);
  float* T1 = (float*)(ws + OFF_T1);
  float* E  = (float*)(ws + OFF_E);
  __bf16* P = (__bf16*)(ws + OFF_P);

  // zero G and s (atomically accumulated)
  hipMemsetAsync(ws, 0, OFF_EK, stream);

  k1_gram<<<dim3(16, 3, 8), dim3(256), 0, stream>>>(x, G, s);
  k1_mirror<<<dim3(64, 8), dim3(256), 0, stream>>>(G);
  k2_vec<<<dim3(8), dim3(512), 0, stream>>>(Wq, Wk, s, ek, eq);
  k2_nt<<<dim3(4, 4, 8), dim3(256), 0, stream>>>(Wk, 0, G, 1, T1,
                                                 nullptr, nullptr, nullptr, nullptr, 0.f, 0);
  k2_nt<<<dim3(4, 4, 8), dim3(256), 0, stream>>>(T1, 1, Wq, 0, E,
                                                 ek, bq, bk, eq, (float)N_DIM, 1);
  k2_softmax<<<dim3(512), dim3(256), 0, stream>>>(E);
  k2_pprime<<<dim3(4, 4, 8), dim3(256), 0, stream>>>(E, Wv, gm, P);
  k2_dvec<<<dim3(8), dim3(256), 0, stream>>>(E, bv, gm, dv);
  k3_out<<<dim3(128, 2, 8), dim3(256), 0, stream>>>(x, P, dv, out);
}

// Round 2
// 236.571 us; speedup vs baseline: 1.1669x; 1.1669x over previous
//
#include <hip/hip_runtime.h>

#define C_DIM 256
#define N_DIM 16384
#define NBATCH 8

typedef __bf16 bf16x4 __attribute__((ext_vector_type(4)));
typedef __bf16 bf16x8 __attribute__((ext_vector_type(8)));
typedef float  f32x4  __attribute__((ext_vector_type(4)));

// ---- workspace layout (bytes) ----
#define OFF_G   0x000000u   // G:  8 x 256 x 256 f32 (2 MiB), atomically accumulated
#define OFF_S   0x200000u   // s:  8 x 256 f32 (row sums of X)
#define OFF_EK  0x202000u   // ek: 8 x 256 f32
#define OFF_EQ  0x204000u   // eq: 8 x 256 f32
#define OFF_D   0x206000u   // d:  8 x 256 f32
#define OFF_T1  0x210000u   // T1: 8 x 256 x 256 f32 (2 MiB)
#define OFF_E   0x410000u   // energy / attention in-place: 8 x 256 x 256 f32 (2 MiB)
#define OFF_P   0x610000u   // P' = gamma*AttT*Wv + I : 8 x 256 x 256 bf16 (1 MiB)

// XOR swizzle for [row][64 x bf16] LDS tiles (128 B rows). Bank-conflict-free
// for both bf16x4 staging writes and bf16x8 fragment reads (measured: 0 conflicts).
__device__ __forceinline__ unsigned sw_off(int row, int kbyte) {
  return (unsigned)(row * 128 + (kbyte ^ ((((row >> 2) ^ row) & 7) << 4)));
}
__device__ __forceinline__ float f4g(const float4& v, int i) {
  return reinterpret_cast<const float*>(&v)[i];
}

// ============================================================================
// K1: G[b] += X_b X_b^T  (bf16 MFMA, split-K over N, 3 quadrants via symmetry)
// Pipelined: prologue reg-load; per iter {bar; LDS-write; bar; prefetch; MFMA}
// grid (16 chunks, 3 quadrants, 8 batches), block 256 (4 waves, 2x2 of 64x64)
// ============================================================================
__global__ __launch_bounds__(256) void k1_gram(const float* __restrict__ x,
                                               float* __restrict__ G,
                                               float* __restrict__ srow) {
  __shared__ __align__(16) char lds[2 * 128 * 128];
  __shared__ float s_lds[128];
  const int qi = blockIdx.y;
  const int qa = (qi == 2) ? 1 : 0;        // quadrants: (0,0),(0,1),(1,1)
  const int qb = (qi == 0) ? 0 : 1;
  const bool diag = (qa == qb);
  const int b = blockIdx.z;
  const float* xb = x + (size_t)b * C_DIM * N_DIM;
  const int tid = threadIdx.x, lane = tid & 63, wave = tid >> 6;
  const int wm = wave >> 1, wn = wave & 1;
  char* Alds = lds;
  char* Blds = lds + 16384;
  const int k4 = tid & 15, rowt = tid >> 4;
  float spart[8];
#pragma unroll
  for (int p = 0; p < 8; ++p) spart[p] = 0.f;
  f32x4 acc[4][4] = {};
  const size_t nbase = (size_t)blockIdx.x * 1024;   // 16 chunks x 1024 = 16384

  float4 va[8], vb[8];
  {  // prologue: load chunk 0 into registers
    const size_t n0 = nbase + 4 * k4;
#pragma unroll
    for (int p = 0; p < 8; ++p) {
      const int row = rowt + p * 16;
      va[p] = *(const float4*)&xb[(size_t)(qa * 128 + row) * N_DIM + n0];
      if (!diag) vb[p] = *(const float4*)&xb[(size_t)(qb * 128 + row) * N_DIM + n0];
    }
  }

  for (int ks = 0; ks < 16; ++ks) {
    __syncthreads();   // previous MFMA done reading LDS (and drains this iter's loads)
#pragma unroll
    for (int p = 0; p < 8; ++p) {
      const int row = rowt + p * 16;
      if (diag) spart[p] += va[p].x + va[p].y + va[p].z + va[p].w;
      bf16x4 ha = { (__bf16)va[p].x, (__bf16)va[p].y, (__bf16)va[p].z, (__bf16)va[p].w };
      *(bf16x4*)(Alds + sw_off(row, 8 * k4)) = ha;
      if (!diag) {
        bf16x4 hb = { (__bf16)vb[p].x, (__bf16)vb[p].y, (__bf16)vb[p].z, (__bf16)vb[p].w };
        *(bf16x4*)(Blds + sw_off(row, 8 * k4)) = hb;
      }
    }
    __syncthreads();
    if (ks < 15) {     // prefetch next chunk: loads fly under the MFMA phase
      const size_t n0 = nbase + (size_t)(ks + 1) * 64 + 4 * k4;
#pragma unroll
      for (int p = 0; p < 8; ++p) {
        const int row = rowt + p * 16;
        va[p] = *(const float4*)&xb[(size_t)(qa * 128 + row) * N_DIM + n0];
        if (!diag) vb[p] = *(const float4*)&xb[(size_t)(qb * 128 + row) * N_DIM + n0];
      }
    }
    const char* Bsrc = diag ? Alds : Blds;
#pragma unroll
    for (int kk = 0; kk < 2; ++kk) {
      bf16x8 af[4], bfr[4];
      const int kbyte = (kk * 32 + (lane >> 4) * 8) * 2;
#pragma unroll
      for (int mi = 0; mi < 4; ++mi)
        af[mi] = *(const bf16x8*)(Alds + sw_off(wm * 64 + mi * 16 + (lane & 15), kbyte));
#pragma unroll
      for (int ni = 0; ni < 4; ++ni)
        bfr[ni] = *(const bf16x8*)(Bsrc + sw_off(wn * 64 + ni * 16 + (lane & 15), kbyte));
#pragma unroll
      for (int mi = 0; mi < 4; ++mi)
#pragma unroll
        for (int ni = 0; ni < 4; ++ni)
          acc[mi][ni] = __builtin_amdgcn_mfma_f32_16x16x32_bf16(af[mi], bfr[ni], acc[mi][ni], 0, 0, 0);
    }
  }

  float* Gb = G + (size_t)b * 65536;
#pragma unroll
  for (int mi = 0; mi < 4; ++mi)
#pragma unroll
    for (int ni = 0; ni < 4; ++ni)
#pragma unroll
      for (int r = 0; r < 4; ++r) {
        const int gr = qa * 128 + wm * 64 + mi * 16 + (lane >> 4) * 4 + r;
        const int gc = qb * 128 + wn * 64 + ni * 16 + (lane & 15);
        atomicAdd(&Gb[gr * 256 + gc], acc[mi][ni][r]);
      }

  if (diag) {
    __syncthreads();
    if (tid < 128) s_lds[tid] = 0.f;
    __syncthreads();
#pragma unroll
    for (int p = 0; p < 8; ++p) atomicAdd(&s_lds[rowt + p * 16], spart[p]);
    __syncthreads();
    if (tid < 128) atomicAdd(&srow[b * 256 + qa * 128 + tid], s_lds[tid]);
  }
}

// Fused: mirror lower-left quadrant of symmetric G  +  ek = Wk*s, eq = Wq*s
// grid (33, 8), block 512. blockIdx.x==32 does the vec work.
__global__ void k2_mv(float* __restrict__ G, const float* __restrict__ Wq,
                      const float* __restrict__ Wk, const float* __restrict__ s,
                      float* __restrict__ ek, float* __restrict__ eq) {
  const int b = blockIdx.y;
  if (blockIdx.x == 32) {
    const int t = threadIdx.x;
    const float* sb = s + b * 256;
    if (t < 256) {
      float a = 0.f;
      for (int i = 0; i < 256; ++i) a += Wk[t * 256 + i] * sb[i];
      ek[b * 256 + t] = a;
    } else {
      const int j = t - 256;
      float a = 0.f;
      for (int i = 0; i < 256; ++i) a += Wq[j * 256 + i] * sb[i];
      eq[b * 256 + j] = a;
    }
  } else {
    const int idx = blockIdx.x * 512 + threadIdx.x;   // 0..16383
    const int a = idx >> 7, c = idx & 127;
    float* Gb = G + (size_t)b * 65536;
    Gb[(size_t)(128 + c) * 256 + a] = Gb[(size_t)a * 256 + 128 + c];
  }
}

// NT mini-GEMM: C[i][j] = sum_k A[i][k] * B[j][k]   (256x256x256, fp32)
__global__ __launch_bounds__(256) void k2_nt(const float* __restrict__ Ag, int abatch,
                                             const float* __restrict__ Bg, int bbatch,
                                             float* __restrict__ Cg,
                                             const float* __restrict__ ek,
                                             const float* __restrict__ bq,
                                             const float* __restrict__ bk,
                                             const float* __restrict__ eq,
                                             float Nf, int bias) {
  const int b = blockIdx.z;
  const float* A = Ag + (abatch ? (size_t)b * 65536 : 0);
  const float* B = Bg + (bbatch ? (size_t)b * 65536 : 0);
  float* Cb = Cg + (size_t)b * 65536;
  const int i0 = blockIdx.y * 64 + 4 * (threadIdx.x >> 4);
  const int c0 = blockIdx.x * 64 + 4 * (threadIdx.x & 15);
  float acc[4][4] = {};
  for (int k = 0; k < 256; k += 4) {
    float4 av[4], bv4[4];
#pragma unroll
    for (int r = 0; r < 4; ++r) av[r] = *(const float4*)&A[(size_t)(i0 + r) * 256 + k];
#pragma unroll
    for (int s2 = 0; s2 < 4; ++s2) bv4[s2] = *(const float4*)&B[(size_t)(c0 + s2) * 256 + k];
#pragma unroll
    for (int r = 0; r < 4; ++r)
#pragma unroll
      for (int s2 = 0; s2 < 4; ++s2)
        acc[r][s2] += av[r].x * bv4[s2].x + av[r].y * bv4[s2].y +
                      av[r].z * bv4[s2].z + av[r].w * bv4[s2].w;
  }
#pragma unroll
  for (int r = 0; r < 4; ++r)
#pragma unroll
    for (int s2 = 0; s2 < 4; ++s2) {
      const int i = i0 + r, j = c0 + s2;
      float v = acc[r][s2];
      if (bias) v += ek[b * 256 + i] * bq[j] + bk[i] * (eq[b * 256 + j] + Nf * bq[j]);
      Cb[(size_t)i * 256 + j] = v;
    }
}

// row-softmax over last axis, in place. One wave per 256-float row.
__global__ __launch_bounds__(256) void k2_softmax(float* __restrict__ E) {
  const int gw = blockIdx.x * 4 + (threadIdx.x >> 6);   // 0..2047
  const int b = gw >> 8, i = gw & 255;
  const int lane = threadIdx.x & 63;
  float* row = E + (size_t)b * 65536 + (size_t)i * 256;
  float4 v = *(const float4*)&row[lane * 4];
  float m = fmaxf(fmaxf(v.x, v.y), fmaxf(v.z, v.w));
  for (int o = 32; o > 0; o >>= 1) m = fmaxf(m, __shfl_xor(m, o));
  v.x = __expf(v.x - m); v.y = __expf(v.y - m);
  v.z = __expf(v.z - m); v.w = __expf(v.w - m);
  float sum = v.x + v.y + v.z + v.w;
  for (int o = 32; o > 0; o >>= 1) sum += __shfl_xor(sum, o);
  const float inv = 1.0f / sum;
  v.x *= inv; v.y *= inv; v.z *= inv; v.w *= inv;
  *(float4*)&row[lane * 4] = v;
}

// P'[j][c] = gamma * sum_i Att[i][j] * Wv[i][c] + (j==c), stored bf16.
// Fused: blocks with blockIdx.x==0 also compute d[j] = gamma*sum_i Att[i][j]*bv[i].
__global__ __launch_bounds__(256) void k2_pprime(const float* __restrict__ Att,
                                                 const float* __restrict__ Wv,
                                                 const float* __restrict__ bv,
                                                 const float* __restrict__ gm,
                                                 __bf16* __restrict__ P,
                                                 float* __restrict__ dv) {
  const int b = blockIdx.z;
  const float* Ab = Att + (size_t)b * 65536;
  const int j0 = blockIdx.y * 64 + 4 * (threadIdx.x >> 4);
  const int c0 = blockIdx.x * 64 + 4 * (threadIdx.x & 15);
  float acc[4][4] = {};
#pragma unroll 4
  for (int i = 0; i < 256; ++i) {
    float4 av = *(const float4*)&Ab[(size_t)i * 256 + j0];
    float4 wv = *(const float4*)&Wv[(size_t)i * 256 + c0];
#pragma unroll
    for (int r = 0; r < 4; ++r) {
      const float a = f4g(av, r);
#pragma unroll
      for (int s2 = 0; s2 < 4; ++s2) acc[r][s2] += a * f4g(wv, s2);
    }
  }
  const float g = gm[0];
  __bf16* Pb = P + (size_t)b * 65536;
#pragma unroll
  for (int r = 0; r < 4; ++r)
#pragma unroll
    for (int s2 = 0; s2 < 4; ++s2) {
      const float v = g * acc[r][s2] + ((j0 + r) == (c0 + s2) ? 1.f : 0.f);
      Pb[(size_t)(j0 + r) * 256 + c0 + s2] = (__bf16)v;
    }
  if (blockIdx.x == 0 && threadIdx.x < 64) {
    const int j = blockIdx.y * 64 + threadIdx.x;
    float a = 0.f;
    for (int i = 0; i < 256; ++i) a += Ab[(size_t)i * 256 + j] * bv[i];
    dv[b * 256 + j] = g * a;
  }
}

// ============================================================================
// K3: out[b] = P'_b * X_b + d 1^T  (bf16 MFMA; residual+gamma folded into P')
// Pipelined like k1. grid (128 n-tiles, 2 j-tiles, 8 batches), block 256.
// ============================================================================
__global__ __launch_bounds__(256) void k3_out(const float* __restrict__ x,
                                              const __bf16* __restrict__ P,
                                              const float* __restrict__ dvec,
                                              float* __restrict__ out) {
  __shared__ __align__(16) char lds[2 * 128 * 128];
  const int b = blockIdx.z, jt = blockIdx.y, nt = blockIdx.x;
  const float* xb = x + (size_t)b * C_DIM * N_DIM;
  const __bf16* Pb = P + (size_t)b * 65536;
  const int tid = threadIdx.x, lane = tid & 63, wave = tid >> 6;
  const int wm = wave >> 1, wn = wave & 1;
  char* Alds = lds;          // P' tile: [128 j][64 c]
  char* Blds = lds + 16384;  // Xt tile: [128 n][64 c]
  const int k4 = tid & 15, rowt = tid >> 4;
  const int nq = tid & 31, cq = tid >> 5;
  const int n0 = nt * 128;
  f32x4 acc[4][4] = {};

  bf16x4 pa[8];
  float4 xv[2][4];
  {  // prologue: load c-chunk 0
#pragma unroll
    for (int p = 0; p < 8; ++p)
      pa[p] = *(const bf16x4*)&Pb[(size_t)(jt * 128 + rowt + p * 16) * 256 + 4 * k4];
#pragma unroll
    for (int h = 0; h < 2; ++h) {
      const int cc = 4 * cq + 32 * h;
#pragma unroll
      for (int r = 0; r < 4; ++r)
        xv[h][r] = *(const float4*)&xb[(size_t)(cc + r) * N_DIM + n0 + 4 * nq];
    }
  }

  for (int ks = 0; ks < 4; ++ks) {
    __syncthreads();
#pragma unroll
    for (int p = 0; p < 8; ++p)
      *(bf16x4*)(Alds + sw_off(rowt + p * 16, 8 * k4)) = pa[p];
#pragma unroll
    for (int h = 0; h < 2; ++h) {
      const int cb = (4 * cq + 32 * h) * 2;   // byte offset of c within row
#pragma unroll
      for (int i = 0; i < 4; ++i) {           // 4x4 register transpose
        bf16x4 t = { (__bf16)f4g(xv[h][0], i), (__bf16)f4g(xv[h][1], i),
                     (__bf16)f4g(xv[h][2], i), (__bf16)f4g(xv[h][3], i) };
        *(bf16x4*)(Blds + sw_off(4 * nq + i, cb)) = t;
      }
    }
    __syncthreads();
    if (ks < 3) {   // prefetch next c-chunk under MFMA
      const int c0 = (ks + 1) * 64;
#pragma unroll
      for (int p = 0; p < 8; ++p)
        pa[p] = *(const bf16x4*)&Pb[(size_t)(jt * 128 + rowt + p * 16) * 256 + c0 + 4 * k4];
#pragma unroll
      for (int h = 0; h < 2; ++h) {
        const int cc = c0 + 4 * cq + 32 * h;
#pragma unroll
        for (int r = 0; r < 4; ++r)
          xv[h][r] = *(const float4*)&xb[(size_t)(cc + r) * N_DIM + n0 + 4 * nq];
      }
    }
#pragma unroll
    for (int kk = 0; kk < 2; ++kk) {
      bf16x8 af[4], bfr[4];
      const int kbyte = (kk * 32 + (lane >> 4) * 8) * 2;
#pragma unroll
      for (int mi = 0; mi < 4; ++mi)
        af[mi] = *(const bf16x8*)(Alds + sw_off(wm * 64 + mi * 16 + (lane & 15), kbyte));
#pragma unroll
      for (int ni = 0; ni < 4; ++ni)
        bfr[ni] = *(const bf16x8*)(Blds + sw_off(wn * 64 + ni * 16 + (lane & 15), kbyte));
#pragma unroll
      for (int mi = 0; mi < 4; ++mi)
#pragma unroll
        for (int ni = 0; ni < 4; ++ni)
          acc[mi][ni] = __builtin_amdgcn_mfma_f32_16x16x32_bf16(af[mi], bfr[ni], acc[mi][ni], 0, 0, 0);
    }
  }

  float* ob = out + (size_t)b * C_DIM * N_DIM;
#pragma unroll
  for (int mi = 0; mi < 4; ++mi)
#pragma unroll
    for (int ni = 0; ni < 4; ++ni)
#pragma unroll
      for (int r = 0; r < 4; ++r) {
        const int j = jt * 128 + wm * 64 + mi * 16 + (lane >> 4) * 4 + r;
        const int n = n0 + wn * 64 + ni * 16 + (lane & 15);
        ob[(size_t)j * N_DIM + n] = acc[mi][ni][r] + dvec[b * 256 + j];
      }
}

extern "C" void kernel_launch(void* const* d_in, const int* in_sizes, int n_in,
                              void* d_out, int out_size, void* d_ws, size_t ws_size,
                              hipStream_t stream) {
  const float* x  = (const float*)d_in[0];
  const float* Wq = (const float*)d_in[1];
  const float* bq = (const float*)d_in[2];
  const float* Wk = (const float*)d_in[3];
  const float* bk = (const float*)d_in[4];
  const float* Wv = (const float*)d_in[5];
  const float* bv = (const float*)d_in[6];
  const float* gm = (const float*)d_in[7];
  float* out = (float*)d_out;
  char* ws = (char*)d_ws;
  float* G  = (float*)(ws + OFF_G);
  float* s  = (float*)(ws + OFF_S);
  float* ek = (float*)(ws + OFF_EK);
  float* eq = (float*)(ws + OFF_EQ);
  float* dv = (float*)(ws + OFF_D);
  float* T1 = (float*)(ws + OFF_T1);
  float* E  = (float*)(ws + OFF_E);
  __bf16* P = (__bf16*)(ws + OFF_P);

  // zero G and s (atomically accumulated)
  hipMemsetAsync(ws, 0, OFF_EK, stream);

  k1_gram<<<dim3(16, 3, 8), dim3(256), 0, stream>>>(x, G, s);
  k2_mv<<<dim3(33, 8), dim3(512), 0, stream>>>(G, Wq, Wk, s, ek, eq);
  k2_nt<<<dim3(4, 4, 8), dim3(256), 0, stream>>>(Wk, 0, G, 1, T1,
                                                 nullptr, nullptr, nullptr, nullptr, 0.f, 0);
  k2_nt<<<dim3(4, 4, 8), dim3(256), 0, stream>>>(T1, 1, Wq, 0, E,
                                                 ek, bq, bk, eq, (float)N_DIM, 1);
  k2_softmax<<<dim3(512), dim3(256), 0, stream>>>(E);
  k2_pprime<<<dim3(4, 4, 8), dim3(256), 0, stream>>>(E, Wv, bv, gm, P, dv);
  k3_out<<<dim3(128, 2, 8), dim3(256), 0, stream>>>(x, P, dv, out);
}